// Round 2
// 522.795 us; speedup vs baseline: 1.1720x; 1.1720x over previous
//
#include <hip/hip_runtime.h>
#include <math.h>

#define N 8192
#define IN_DIM 128
#define HID 32

#define RB 128          // rows per spmm block
#define KT 64           // k-tile
#define SK 16           // split-K factor (1024 blocks -> 4 co-resident blocks/CU)
#define KCHUNK (N / SK) // 512

__device__ __forceinline__ void fma4(float4& acc, float a, const float4& b) {
    acc.x = fmaf(a, b.x, acc.x);
    acc.y = fmaf(a, b.y, acc.y);
    acc.z = fmaf(a, b.z, acc.z);
    acc.w = fmaf(a, b.w, acc.w);
}

// degree[i] = 1 + sum_j adj[i][j];  dinv[i] = 1/sqrt(max(degree,1))
__global__ __launch_bounds__(256) void k_degree(const float* __restrict__ adj,
                                                float* __restrict__ dinv) {
    int row = blockIdx.x;
    const float4* rp = (const float4*)(adj + (size_t)row * N);
    int t = threadIdx.x;
    float s = 0.f;
#pragma unroll
    for (int i = 0; i < 8; ++i) {
        float4 v = rp[t + i * 256];
        s += v.x + v.y + v.z + v.w;
    }
    for (int off = 32; off > 0; off >>= 1) s += __shfl_down(s, off, 64);
    __shared__ float red[4];
    if ((t & 63) == 0) red[t >> 6] = s;
    __syncthreads();
    if (t == 0) {
        float deg = red[0] + red[1] + red[2] + red[3] + 1.0f;  // +1 self loop
        deg = fmaxf(deg, 1.0f);
        dinv[row] = 1.0f / sqrtf(deg);
    }
}

// Zs[i][c] = dinv[i] * (x[i] @ W1 + b1)[c]   (x: [N,128], W1: [128,32])
__global__ __launch_bounds__(256) void k_z1(const float* __restrict__ x,
                                            const float* __restrict__ W1,
                                            const float* __restrict__ b1,
                                            const float* __restrict__ dinv,
                                            float* __restrict__ Zs) {
    __shared__ float Ws[IN_DIM * HID];  // 4096 floats
    __shared__ float xs[8 * IN_DIM];    // 1024 floats
    int t = threadIdx.x;
    int row0 = blockIdx.x * 8;
#pragma unroll
    for (int i = 0; i < 4; ++i)
        *(float4*)&Ws[(i * 256 + t) * 4] = *(const float4*)&W1[(i * 256 + t) * 4];
    *(float4*)&xs[t * 4] = *(const float4*)&x[(size_t)row0 * IN_DIM + t * 4];
    __syncthreads();
    int r = t >> 5, c = t & 31;
    float acc = b1[c];
#pragma unroll 8
    for (int k = 0; k < IN_DIM; ++k) acc = fmaf(xs[r * IN_DIM + k], Ws[k * HID + c], acc);
    int row = row0 + r;
    Zs[(size_t)row * HID + c] = dinv[row] * acc;
}

// P[sk] = adj[rows, kchunk_sk] @ Zs[kchunk_sk, 32]   (plain stores, no atomics)
// As is XOR-swizzled: element (row, fi) stored at float4 slot fi ^ ((row>>1)&7).
// Read pattern (16 distinct rows, fixed fi) then lands on all 8 bank groups
// -> 2 addrs/bank (free per m136) instead of the padded layout's 4-way.
__global__ __launch_bounds__(256) void k_spmm(const float* __restrict__ adj,
                                              const float* __restrict__ Zs,
                                              float* __restrict__ P) {
    __shared__ float As[RB * KT];   // 32 KB, swizzled
    __shared__ float Bs[KT][HID];   // 8 KB
    int t = threadIdx.x;
    int r0 = blockIdx.x * RB;
    int k0 = blockIdx.y * KCHUNK;
    int cg = t & 3;           // 4 col groups of 8
    int rp2 = (t >> 2) * 2;   // row pair base 0..126
    int e = (rp2 >> 1) & 7;   // swizzle key (same for rp2 and rp2+1)
    float4 acc00 = {0, 0, 0, 0}, acc01 = {0, 0, 0, 0};
    float4 acc10 = {0, 0, 0, 0}, acc11 = {0, 0, 0, 0};

    for (int kt = k0; kt < k0 + KCHUNK; kt += KT) {
        // stage A tile: 128 rows x 64 k, swizzled float4 slots
#pragma unroll
        for (int i = 0; i < 8; ++i) {
            int f = i * 256 + t;         // float4 index in tile
            int row = f >> 4;            // 16 float4 per row
            int fi = f & 15;
            int sfi = fi ^ ((row >> 1) & 7);
            *(float4*)&As[row * KT + sfi * 4] =
                *(const float4*)&adj[(size_t)(r0 + row) * N + kt + fi * 4];
        }
        // stage B tile: 64 x 32 floats, fully contiguous in global
#pragma unroll
        for (int i = 0; i < 2; ++i) {
            int f = i * 256 + t;
            ((float4*)&Bs[0][0])[f] = ((const float4*)(Zs + (size_t)kt * HID))[f];
        }
        __syncthreads();
#pragma unroll
        for (int kk = 0; kk < KT; kk += 4) {
            int s0 = ((kk >> 2) ^ e) * 4;  // swizzled read slot for this row pair
            float a0[4], a1[4];
            *(float4*)a0 = *(const float4*)&As[rp2 * KT + s0];
            *(float4*)a1 = *(const float4*)&As[(rp2 + 1) * KT + s0];
#pragma unroll
            for (int j = 0; j < 4; ++j) {
                float4 z0 = *(const float4*)&Bs[kk + j][cg * 8];
                float4 z1 = *(const float4*)&Bs[kk + j][cg * 8 + 4];
                fma4(acc00, a0[j], z0);
                fma4(acc01, a0[j], z1);
                fma4(acc10, a1[j], z0);
                fma4(acc11, a1[j], z1);
            }
        }
        __syncthreads();
    }

    float* p0 = P + (size_t)blockIdx.y * (N * HID) + (size_t)(r0 + rp2) * HID + cg * 8;
    float* p1 = p0 + HID;
    *(float4*)(p0)     = acc00;
    *(float4*)(p0 + 4) = acc01;
    *(float4*)(p1)     = acc10;
    *(float4*)(p1 + 4) = acc11;
}

// H = relu(dinv * (sum_sk P[sk] + Zs)); then Zout = dinv * (H @ W2 + b2)   (fused fin+z2)
__global__ __launch_bounds__(256) void k_fin_z2(const float* __restrict__ P,
                                                const float* __restrict__ Zin,
                                                const float* __restrict__ dinv,
                                                const float* __restrict__ W2,
                                                const float* __restrict__ b2,
                                                float* __restrict__ Zout) {
    __shared__ float Ws[HID * HID];  // 1024 floats
    __shared__ float hs[8][HID];
    int t = threadIdx.x;
    int row0 = blockIdx.x * 8;
    *(float4*)&Ws[t * 4] = *(const float4*)&W2[t * 4];
    int r = t >> 5, c = t & 31;
    size_t idx = (size_t)row0 * HID + t;   // 256 consecutive elements
    float v = Zin[idx];
#pragma unroll
    for (int s = 0; s < SK; ++s) v += P[(size_t)s * (N * HID) + idx];
    int row = row0 + r;
    hs[r][c] = fmaxf(dinv[row] * v, 0.f);
    __syncthreads();
    float acc = b2[c];
#pragma unroll
    for (int k = 0; k < HID; ++k) acc = fmaf(hs[r][k], Ws[k * HID + c], acc);
    Zout[idx] = dinv[row] * acc;
}

// H = relu(dinv * (sum_sk P[sk] + Zs)); out[i] = H[i] @ W3 + b3   (fused fin+out)
__global__ __launch_bounds__(256) void k_fin_out(const float* __restrict__ P,
                                                 const float* __restrict__ Zin,
                                                 const float* __restrict__ dinv,
                                                 const float* __restrict__ W3,
                                                 const float* __restrict__ b3,
                                                 float* __restrict__ out) {
    int t = threadIdx.x;
    size_t idx = (size_t)blockIdx.x * 256 + t;
    int row = (int)(idx >> 5);
    int c = t & 31;
    float v = Zin[idx];
#pragma unroll
    for (int s = 0; s < SK; ++s) v += P[(size_t)s * (N * HID) + idx];
    float h = fmaxf(dinv[row] * v, 0.f);
    float hw = h * W3[c];
#pragma unroll
    for (int off = 16; off > 0; off >>= 1) hw += __shfl_xor(hw, off, 32);
    if (c == 0) out[row] = hw + b3[0];
}

extern "C" void kernel_launch(void* const* d_in, const int* in_sizes, int n_in,
                              void* d_out, int out_size, void* d_ws, size_t ws_size,
                              hipStream_t stream) {
    const float* x   = (const float*)d_in[0];
    const float* adj = (const float*)d_in[1];
    const float* W1  = (const float*)d_in[2];
    const float* b1  = (const float*)d_in[3];
    const float* W2  = (const float*)d_in[4];
    const float* b2  = (const float*)d_in[5];
    const float* W3  = (const float*)d_in[6];
    const float* b3  = (const float*)d_in[7];
    float* out = (float*)d_out;

    float* dinv = (float*)d_ws;               // N floats
    float* Zs1  = dinv + N;                   // N*32 floats (1 MB)
    float* Zs2  = Zs1 + (size_t)N * HID;      // N*32 floats (1 MB)
    float* P    = Zs2 + (size_t)N * HID;      // SK*N*32 floats (16 MB)

    k_degree<<<N, 256, 0, stream>>>(adj, dinv);
    k_z1<<<N / 8, 256, 0, stream>>>(x, W1, b1, dinv, Zs1);

    k_spmm<<<dim3(N / RB, SK), 256, 0, stream>>>(adj, Zs1, P);
    k_fin_z2<<<N / 8, 256, 0, stream>>>(P, Zs1, dinv, W2, b2, Zs2);

    k_spmm<<<dim3(N / RB, SK), 256, 0, stream>>>(adj, Zs2, P);
    k_fin_out<<<N * HID / 256, 256, 0, stream>>>(P, Zs2, dinv, W3, b3, out);
}